// Round 7
// baseline (182.625 us; speedup 1.0000x reference)
//
#include <hip/hip_runtime.h>

// F0 via autocorrelation argmax — round 20: tier-1-only loop + worklist finish.
//   SR=16000, HOP=256, FRAME_LEN=512, pad=256, T=163840, B=64, n_frames=641
//   lags p in [32,256). argmax of RAW autocorrelation == reference argmax.
//
// Evidence r13-r19: single-shot one-frame blocks pin at ~1.5 resident
// blocks/CU (dispatch churn; body cuts return <=5% because latency-bound at
// ~6 waves/CU). The two "high-residency failed" rounds are confounded:
// r14-t1 ran at 32 VGPR (forced read/MFMA serialization, 11.5us/frame);
// r18 at 176 VGPR (slow at LOW occupancy too). Clean-body high residency
// is untested -> r20 tests it while dodging the r11/12 allocator trap
// (tiers-2/3 inside a loop):
//   f0_t1 : tier-1 ONLY loop. 1282 blocks x 4 waves x 8 frames. Hi-only
//           staggered LDS (25.5KB/block -> 6 blocks/CU). launch_bounds
//           (256,4). Rejects -> device-global worklist.
//   f0_t23: full r19 finish (tier-1 acc recompute + tier-2 + tier-3),
//           bit-identical arithmetic, grid-stride over worklist (~15%).
// vs r14 pipeline: no VGPR cripple, ONE finish kernel (one tail), bijective
// XCD swizzle (m204; 1282 % 8 != 0).
//
// GEMM cast (validated r8-r19, absmax 0.0): y = frame zero-extended,
//   A[m,k]=y[k-16m], B[k,n]=y[k+32+n] => D[m,n]=AC[32+16m+n]
//   15 mfma_f32_16x16x32_f16 (NC=15; c=15 contributes exactly +0.0).
//   Staggered hi copies C_s[e]=y[e-240+s], s=0..3, CP=408 (24 mod 32:
//   conflict-free b64 B-reads, verified r19: 6.5M -> 0.85M conflict cyc).
// Reductions on VALU: DPP quad_perm/row_ror + permlane16/32_swap (fail-safe:
// wrong orientation inflates v2 -> gates reject -> exact tier-3).
// Tiers: E1 = 2^-10*Q + 0.05 ; tier-2 double-f16 split E2 = 1e-4*Q + 0.02 ;
// tier-3 fp64 register tile exact (cold).

#define SR_F 16000.0f
#define HOP 256
#define FRAME_LEN 512
#define PAD 256
#define T_LEN 163840
#define N_FRAMES 641
#define TOTAL (64 * N_FRAMES)   // 41024
#define MIN_PERIOD 32
#define N_LAGS 224
#define WPB 4              // waves per block
#define CP 408             // hi-copy stride in dwords; 408 mod 32 = 24
#define T1_DW (4 * CP)     // 1632 dw/wave (hi copies only) -> 26112 B/block
#define L0_OFF 1632        // lo even copy (t23 layout)
#define L1_OFF 2032        // lo odd copy
#define T23_DW 2432        // t23 dwords per wave slice (38912 B/block)
#define NC 15              // K-steps: c=15 contributes exactly zero
#define T1_BLOCKS 1282     // x4 waves x8 frames = 41024 exactly
#define NF 8               // frames per wave in f0_t1
#define T23_BLOCKS 768
#define T23_STRIDE (T23_BLOCKS * WPB)

typedef _Float16 half8 __attribute__((ext_vector_type(8)));
typedef float floatx4 __attribute__((ext_vector_type(4)));
typedef unsigned int uint2v __attribute__((ext_vector_type(2)));

__device__ unsigned int g_cnt2;
__device__ unsigned int g_lst2[TOTAL];

__device__ __forceinline__ int swz(int q) { return q ^ ((q >> 3) & 7); }

__device__ __forceinline__ unsigned int pkh(float a, float b) {
    unsigned short ha = __builtin_bit_cast(unsigned short, (_Float16)a);
    unsigned short hb = __builtin_bit_cast(unsigned short, (_Float16)b);
    return (unsigned int)ha | ((unsigned int)hb << 16);
}

// ---- cross-lane on the VALU pipe (keep the DS unit free) ----
#define DPP_XOR1 0xB1    // quad_perm [1,0,3,2]
#define DPP_XOR2 0x4E    // quad_perm [2,3,0,1]
#define DPP_ROR4 0x124   // row_ror:4
#define DPP_ROR8 0x128   // row_ror:8

template <int CTRL> __device__ __forceinline__ int dppi(int x) {
    return __builtin_amdgcn_update_dpp(0, x, CTRL, 0xF, 0xF, false);
}
template <int CTRL> __device__ __forceinline__ float dppf(float x) {
    return __builtin_bit_cast(float, dppi<CTRL>(__builtin_bit_cast(int, x)));
}

// permlane swaps: contract — pr[0]+pr[1] == self+partner;
// (sel ? pr[0] : pr[1]) == partner, sel = oddrow (16) / upper half (32).
__device__ __forceinline__ uint2v pl16sw(unsigned int x, bool sel) {
#if __has_builtin(__builtin_amdgcn_permlane16_swap)
    (void)sel;
    return __builtin_amdgcn_permlane16_swap(x, x, false, false);
#else
    unsigned int p = (unsigned int)__shfl_xor((int)x, 16);
    uint2v r; r[0] = sel ? p : x; r[1] = sel ? x : p; return r;
#endif
}
__device__ __forceinline__ uint2v pl32sw(unsigned int x, bool sel) {
#if __has_builtin(__builtin_amdgcn_permlane32_swap)
    (void)sel;
    return __builtin_amdgcn_permlane32_swap(x, x, false, false);
#else
    unsigned int p = (unsigned int)__shfl_xor((int)x, 32);
    uint2v r; r[0] = sel ? p : x; r[1] = sel ? x : p; return r;
#endif
}

// full-wave sum, zero DS ops
__device__ __forceinline__ float wave_sum(float x, bool oddrow, bool hihalf) {
    x += dppf<DPP_XOR1>(x);
    x += dppf<DPP_XOR2>(x);
    x += dppf<DPP_ROR4>(x);
    x += dppf<DPP_ROR8>(x);
    uint2v p = pl16sw(__builtin_bit_cast(unsigned int, x), oddrow);
    x = __builtin_bit_cast(float, p[0]) + __builtin_bit_cast(float, p[1]);
    p = pl32sw(__builtin_bit_cast(unsigned int, x), hihalf);
    x = __builtin_bit_cast(float, p[0]) + __builtin_bit_cast(float, p[1]);
    return x;
}

__device__ __forceinline__
void top2_comb(float& v1, int& i1, float& v2, float ov1, int oi1, float ov2) {
    bool take = (ov1 > v1) || (ov1 == v1 && oi1 < i1);
    float lose = take ? v1 : ov1;
    if (take) { v1 = ov1; i1 = oi1; }
    v2 = fmaxf(fmaxf(v2, ov2), lose);
}

template <int CTRL> __device__ __forceinline__
void top2_dpp(float& v1, int& i1, float& v2) {
    float ov1 = dppf<CTRL>(v1);
    int   oi1 = dppi<CTRL>(i1);
    float ov2 = dppf<CTRL>(v2);
    top2_comb(v1, i1, v2, ov1, oi1, ov2);
}

// per-lane top2 over 4 regs, then full-wave combine — zero DS ops
__device__ __forceinline__
void top2_full(floatx4 acc, int qd, int nn, bool oddrow, bool hihalf,
               float& v1, int& i1, float& v2) {
    v1 = acc[0];
    i1 = 64*qd + nn;
    v2 = -__builtin_inff();
    #pragma unroll
    for (int r = 1; r < 4; ++r) {
        float cv = (4*qd + r < 14) ? acc[r] : -__builtin_inff();
        bool take = (cv > v1);
        float lose = take ? v1 : cv;
        if (take) { v1 = cv; i1 = 64*qd + 16*r + nn; }
        v2 = fmaxf(v2, lose);
    }
    top2_dpp<DPP_XOR1>(v1, i1, v2);
    top2_dpp<DPP_XOR2>(v1, i1, v2);
    top2_dpp<DPP_ROR4>(v1, i1, v2);
    top2_dpp<DPP_ROR8>(v1, i1, v2);
    {
        uint2v a = pl16sw(__builtin_bit_cast(unsigned int, v1), oddrow);
        uint2v b = pl16sw((unsigned int)i1, oddrow);
        uint2v c = pl16sw(__builtin_bit_cast(unsigned int, v2), oddrow);
        float ov1 = __builtin_bit_cast(float, oddrow ? a[0] : a[1]);
        int   oi1 = (int)(oddrow ? b[0] : b[1]);
        float ov2 = __builtin_bit_cast(float, oddrow ? c[0] : c[1]);
        top2_comb(v1, i1, v2, ov1, oi1, ov2);
    }
    {
        uint2v a = pl32sw(__builtin_bit_cast(unsigned int, v1), hihalf);
        uint2v b = pl32sw((unsigned int)i1, hihalf);
        uint2v c = pl32sw(__builtin_bit_cast(unsigned int, v2), hihalf);
        float ov1 = __builtin_bit_cast(float, hihalf ? a[0] : a[1]);
        int   oi1 = (int)(hihalf ? b[0] : b[1]);
        float ov2 = __builtin_bit_cast(float, hihalf ? c[0] : c[1]);
        top2_comb(v1, i1, v2, ov1, oi1, ov2);
    }
}

// stage 4 staggered hi copies: C_s[e] = y[e-240+s], s=0..3 (validated r15/r19)
__device__ __forceinline__ void write_hi4(unsigned int* c0_, unsigned int* c1_,
                                          unsigned int* c2_, unsigned int* c3_,
                                          unsigned int u10, unsigned int u11,
                                          unsigned int u20, unsigned int u21,
                                          int lane) {
    *(unsigned long long*)(c0_ + 120 + 2*lane) =
        ((unsigned long long)u11 << 32) | u10;
    *(unsigned long long*)(c0_ + 248 + 2*lane) =
        ((unsigned long long)u21 << 32) | u20;
    unsigned int a  = __shfl(u10, (lane + 1) & 63);
    unsigned int bb = __shfl(u20, (lane + 1) & 63);
    unsigned int n1 = (lane == 63) ? bb : a;
    unsigned int n2 = (lane == 63) ? 0u : bb;
    unsigned int o10 = (u10 >> 16) | (u11 << 16);
    unsigned int o11 = (u11 >> 16) | (n1 << 16);
    unsigned int o20 = (u20 >> 16) | (u21 << 16);
    unsigned int o21 = (u21 >> 16) | (n2 << 16);
    *(unsigned long long*)(c1_ + 120 + 2*lane) =
        ((unsigned long long)o11 << 32) | o10;
    *(unsigned long long*)(c1_ + 248 + 2*lane) =
        ((unsigned long long)o21 << 32) | o20;
    c2_[119 + 2*lane] = u10; c2_[120 + 2*lane] = u11;
    c2_[247 + 2*lane] = u20; c2_[248 + 2*lane] = u21;
    c3_[119 + 2*lane] = o10; c3_[120 + 2*lane] = o11;
    c3_[247 + 2*lane] = o20; c3_[248 + 2*lane] = o21;
}

// stage lo parity copies (tier-2 only): L0[e]=y[e-240], L1[e]=y[e-239]
__device__ __forceinline__ void write_lo2(unsigned int* l0_, unsigned int* l1_,
                                          unsigned int u10, unsigned int u11,
                                          unsigned int u20, unsigned int u21,
                                          int lane) {
    *(unsigned long long*)(l0_ + 120 + 2*lane) =
        ((unsigned long long)u11 << 32) | u10;
    *(unsigned long long*)(l0_ + 248 + 2*lane) =
        ((unsigned long long)u21 << 32) | u20;
    unsigned int a  = __shfl(u10, (lane + 1) & 63);
    unsigned int bb = __shfl(u20, (lane + 1) & 63);
    unsigned int n1 = (lane == 63) ? bb : a;
    unsigned int n2 = (lane == 63) ? 0u : bb;
    *(unsigned long long*)(l1_ + 120 + 2*lane) =
        ((unsigned long long)(((u11 >> 16) | (n1 << 16))) << 32) |
        ((u10 >> 16) | (u11 << 16));
    *(unsigned long long*)(l1_ + 248 + 2*lane) =
        ((unsigned long long)(((u21 >> 16) | (n2 << 16))) << 32) |
        ((u20 >> 16) | (u21 << 16));
}

__device__ __forceinline__ void emit(float* out, int bf, int i1) {
    float period = (float)(i1 + MIN_PERIOD);
    float f0 = SR_F / (period + 1e-8f);
    out[bf] = fminf(fmaxf(f0, 50.0f), 500.0f);
}

__global__ void f0_zero() {
    if (threadIdx.x == 0) g_cnt2 = 0u;
}

// =================== f0_t1: tier-1-only, 8 frames per wave ===================
__global__ __launch_bounds__(256, 4) void f0_t1(const float* __restrict__ wav,
                                                float* __restrict__ out) {
    __shared__ unsigned int yw[WPB][T1_DW];   // 26112 B -> 6 blocks/CU (LDS)

    const int tid  = threadIdx.x;
    const int wv   = tid >> 6;
    const int lane = tid & 63;
    unsigned int* c0p = yw[wv];
    unsigned int* c1p = c0p + CP;
    unsigned int* c2p = c0p + 2*CP;
    unsigned int* c3p = c0p + 3*CP;

    // bijective XCD swizzle (m204): nwg=1282, q=160, r=2
    const int xcd = blockIdx.x & 7;
    const int bi  = blockIdx.x >> 3;
    const int cblk = (xcd < 2 ? xcd * 161 : 322 + (xcd - 2) * 160) + bi;
    const int bf0  = (cblk * WPB + wv) * NF;     // [0, 41024), exact cover

    const int qd = lane >> 4;
    const int nn = lane & 15;
    const int wA0 = 120 + 4*qd - 8*nn;
    const unsigned int* bhp = c0p + CP*(nn & 3) + 136 + 4*qd + 2*(nn >> 2);
    const bool oddrow = (lane & 16) != 0;
    const bool hihalf = (lane & 32) != 0;

    // one-time margin zeros: C0 bottom (A-reads reach dword 0), all tails.
    // Stable across the loop: payload rewrites cover [119..376) only.
    for (int d = lane; d < 120; d += 64) c0p[d] = 0u;
    if (lane < 28) {
        int d = 374 + lane;
        c0p[d] = 0u; c1p[d] = 0u; c2p[d] = 0u; c3p[d] = 0u;
    }

    for (int j = 0; j < NF; ++j) {
        const int bf = bf0 + j;
        const int b  = bf / N_FRAMES;
        const int f  = bf - b * N_FRAMES;
        const float* __restrict__ x = wav + (size_t)b * T_LEN;
        const int base = f * HOP - PAD;
        const bool fast = (f != 0 && f != N_FRAMES - 1);

        __threadfence_block();   // drain prev iter's LDS reads before overwrite
        float qen = 0.0f;
        if (fast) {
            const float4* g4 = (const float4*)(x + base);   // aligned, in-bounds
            float4 c1 = g4[lane];
            float4 c2 = g4[lane + 64];
            qen = c1.x*c1.x + c1.y*c1.y + c1.z*c1.z + c1.w*c1.w
                + c2.x*c2.x + c2.y*c2.y + c2.z*c2.z + c2.w*c2.w;
            write_hi4(c0p, c1p, c2p, c3p, pkh(c1.x, c1.y), pkh(c1.z, c1.w),
                                          pkh(c2.x, c2.y), pkh(c2.z, c2.w), lane);
        } else {
            for (int t = lane; t < FRAME_LEN; t += 64) {
                int idxr = base + t;
                if (idxr < 0) idxr = -idxr;
                if (idxr >= T_LEN) idxr = 2 * (T_LEN - 1) - idxr;
                float v = x[idxr];
                qen = __builtin_fmaf(v, v, qen);
                unsigned short h = __builtin_bit_cast(unsigned short, (_Float16)v);
                ((unsigned short*)c0p)[240 + t] = h;
                ((unsigned short*)c1p)[239 + t] = h;
                ((unsigned short*)c2p)[238 + t] = h;
                ((unsigned short*)c3p)[237 + t] = h;
            }
        }
        __threadfence_block();

        qen = wave_sum(qen, oddrow, hihalf);

        // tier-1: 15 MFMA (2 chains), b64 B-reads (bit-identical to r19)
        floatx4 acc0 = {0.f, 0.f, 0.f, 0.f};
        floatx4 acc1 = {0.f, 0.f, 0.f, 0.f};
        #pragma unroll
        for (int c = 0; c < NC; ++c) {
            uint4 au = *(const uint4*)(c0p + (wA0 + 16*c));
            unsigned long long bl = *(const unsigned long long*)(bhp + 16*c);
            unsigned long long br = *(const unsigned long long*)(bhp + 16*c + 2);
            uint4 bu; bu.x = (unsigned int)bl; bu.y = (unsigned int)(bl >> 32);
            bu.z = (unsigned int)br; bu.w = (unsigned int)(br >> 32);
            if (c & 1)
                acc1 = __builtin_amdgcn_mfma_f32_16x16x32_f16(
                    __builtin_bit_cast(half8, au), __builtin_bit_cast(half8, bu),
                    acc1, 0, 0, 0);
            else
                acc0 = __builtin_amdgcn_mfma_f32_16x16x32_f16(
                    __builtin_bit_cast(half8, au), __builtin_bit_cast(half8, bu),
                    acc0, 0, 0, 0);
        }
        floatx4 acc = acc0 + acc1;

        float v1, v2; int i1;
        top2_full(acc, qd, nn, oddrow, hihalf, v1, i1, v2);

        const float E1 = 9.765625e-4f * qen + 0.05f;
        if (lane == 0) {
            if (v1 - v2 > 2.0f * E1) {
                emit(out, bf, i1);
            } else {
                unsigned int ii = atomicAdd(&g_cnt2, 1u);
                g_lst2[ii] = (unsigned int)bf;
            }
        }
    }
}

// ============ f0_t23: tier-2 + tier-3 over the worklist (~15%) ============
__global__ __launch_bounds__(256, 2) void f0_t23(const float* __restrict__ wav,
                                                 float* __restrict__ out) {
    __shared__ unsigned int yw[WPB][T23_DW];   // 38912 B/block

    const int tid  = threadIdx.x;
    const int wv   = tid >> 6;
    const int lane = tid & 63;
    unsigned int* c0p = yw[wv];
    unsigned int* c1p = c0p + CP;
    unsigned int* c2p = c0p + 2*CP;
    unsigned int* c3p = c0p + 3*CP;
    unsigned int* l0p = c0p + L0_OFF;
    unsigned int* l1p = c0p + L1_OFF;

    const int qd = lane >> 4;
    const int nn = lane & 15;
    const int par = nn & 1;
    const int wA0 = 120 + 4*qd - 8*nn;
    const unsigned int* bhp = c0p + CP*(nn & 3) + 136 + 4*qd + 2*(nn >> 2);
    const int wB0old = 136 + 4*qd + ((nn - par) >> 1);
    const int seg = lane & 15;
    const bool s0 = (seg & 1), s1 = (seg & 2), s2 = (seg & 4), s3 = (seg & 8);
    const bool oddrow = (lane & 16) != 0;
    const bool hihalf = (lane & 32) != 0;

    // one-time zeros stable across items (tier-3 sw clobbers only dwords
    // 0..575 = C0 + start of C1; C1 payload is rewritten per item).
    for (int d = lane; d < 120; d += 64) l0p[d] = 0u;
    if (lane < 28) {
        int d = 374 + lane;
        c1p[d] = 0u; c2p[d] = 0u; c3p[d] = 0u; l0p[d] = 0u; l1p[d] = 0u;
    }

    const unsigned int cnt = g_cnt2;
    for (unsigned int it = blockIdx.x * WPB + wv; it < cnt; it += T23_STRIDE) {
        const int bf = (int)g_lst2[it];
        const int b  = bf / N_FRAMES;
        const int f  = bf - b * N_FRAMES;
        const float* __restrict__ x = wav + (size_t)b * T_LEN;
        const int base = f * HOP - PAD;
        const bool fast = (f != 0 && f != N_FRAMES - 1);

        __threadfence_block();
        // per-item C0 margin re-zero (tier-3 of a previous item clobbers)
        for (int d = lane; d < 120; d += 64) c0p[d] = 0u;
        if (lane < 28) c0p[374 + lane] = 0u;

        float4 c1, c2;
        float qen = 0.0f;
        if (fast) {
            const float4* g4 = (const float4*)(x + base);
            c1 = g4[lane];
            c2 = g4[lane + 64];
            qen = c1.x*c1.x + c1.y*c1.y + c1.z*c1.z + c1.w*c1.w
                + c2.x*c2.x + c2.y*c2.y + c2.z*c2.z + c2.w*c2.w;
            write_hi4(c0p, c1p, c2p, c3p, pkh(c1.x, c1.y), pkh(c1.z, c1.w),
                                          pkh(c2.x, c2.y), pkh(c2.z, c2.w), lane);
        } else {
            for (int t = lane; t < FRAME_LEN; t += 64) {
                int idxr = base + t;
                if (idxr < 0) idxr = -idxr;
                if (idxr >= T_LEN) idxr = 2 * (T_LEN - 1) - idxr;
                float v = x[idxr];
                qen = __builtin_fmaf(v, v, qen);
                unsigned short h = __builtin_bit_cast(unsigned short, (_Float16)v);
                ((unsigned short*)c0p)[240 + t] = h;
                ((unsigned short*)c1p)[239 + t] = h;
                ((unsigned short*)c2p)[238 + t] = h;
                ((unsigned short*)c3p)[237 + t] = h;
            }
        }
        __threadfence_block();

        qen = wave_sum(qen, oddrow, hihalf);

        // tier-1 acc recompute (bit-identical to f0_t1; gate already failed)
        floatx4 acc0 = {0.f, 0.f, 0.f, 0.f};
        floatx4 acc1 = {0.f, 0.f, 0.f, 0.f};
        #pragma unroll
        for (int c = 0; c < NC; ++c) {
            uint4 au = *(const uint4*)(c0p + (wA0 + 16*c));
            unsigned long long bl = *(const unsigned long long*)(bhp + 16*c);
            unsigned long long br = *(const unsigned long long*)(bhp + 16*c + 2);
            uint4 bu; bu.x = (unsigned int)bl; bu.y = (unsigned int)(bl >> 32);
            bu.z = (unsigned int)br; bu.w = (unsigned int)(br >> 32);
            if (c & 1)
                acc1 = __builtin_amdgcn_mfma_f32_16x16x32_f16(
                    __builtin_bit_cast(half8, au), __builtin_bit_cast(half8, bu),
                    acc1, 0, 0, 0);
            else
                acc0 = __builtin_amdgcn_mfma_f32_16x16x32_f16(
                    __builtin_bit_cast(half8, au), __builtin_bit_cast(half8, bu),
                    acc0, 0, 0, 0);
        }
        floatx4 acc = acc0 + acc1;

        // ==== tier-2: double-f16 split, +30 MFMA (hi*lo + lo*hi) ====
        if (fast) {
            float l0 = c1.x - (float)(_Float16)c1.x;
            float l1 = c1.y - (float)(_Float16)c1.y;
            float l2 = c1.z - (float)(_Float16)c1.z;
            float l3 = c1.w - (float)(_Float16)c1.w;
            float l4 = c2.x - (float)(_Float16)c2.x;
            float l5 = c2.y - (float)(_Float16)c2.y;
            float l6 = c2.z - (float)(_Float16)c2.z;
            float l7 = c2.w - (float)(_Float16)c2.w;
            write_lo2(l0p, l1p, pkh(l0, l1), pkh(l2, l3),
                                pkh(l4, l5), pkh(l6, l7), lane);
        } else {
            for (int t = lane; t < FRAME_LEN; t += 64) {
                int idxr = base + t;
                if (idxr < 0) idxr = -idxr;
                if (idxr >= T_LEN) idxr = 2 * (T_LEN - 1) - idxr;
                float v = x[idxr];
                float l = v - (float)(_Float16)v;
                unsigned short h = __builtin_bit_cast(unsigned short, (_Float16)l);
                ((unsigned short*)l0p)[240 + t] = h;
                ((unsigned short*)l1p)[239 + t] = h;
            }
        }
        __threadfence_block();

        const unsigned int* ybl = par ? l1p : l0p;
        #pragma unroll
        for (int c = 0; c < NC; ++c) {              // hi * lo
            uint4 au = *(const uint4*)(c0p + (wA0 + 16*c));
            const unsigned int* p = ybl + (wB0old + 16*c);
            uint4 bu; bu.x = p[0]; bu.y = p[1]; bu.z = p[2]; bu.w = p[3];
            acc = __builtin_amdgcn_mfma_f32_16x16x32_f16(
                __builtin_bit_cast(half8, au), __builtin_bit_cast(half8, bu),
                acc, 0, 0, 0);
        }
        #pragma unroll
        for (int c = 0; c < NC; ++c) {              // lo * hi
            uint4 au = *(const uint4*)(l0p + (wA0 + 16*c));
            unsigned long long bl = *(const unsigned long long*)(bhp + 16*c);
            unsigned long long br = *(const unsigned long long*)(bhp + 16*c + 2);
            uint4 bu; bu.x = (unsigned int)bl; bu.y = (unsigned int)(bl >> 32);
            bu.z = (unsigned int)br; bu.w = (unsigned int)(br >> 32);
            acc = __builtin_amdgcn_mfma_f32_16x16x32_f16(
                __builtin_bit_cast(half8, au), __builtin_bit_cast(half8, bu),
                acc, 0, 0, 0);
        }

        float v1, v2; int i1;
        top2_full(acc, qd, nn, oddrow, hihalf, v1, i1, v2);

        const float E2 = 1.0e-4f * qen + 0.02f;
        if (v1 - v2 > 2.0f * E2) {
            if (lane == 0) emit(out, bf, i1);
            continue;
        }

        // ============ tier-3: fp64 register tile (exact) ============
        float* sw = (float*)c0p;   // dwords 0..575 (C0 + C1 head; restaged)
        if (fast) {
            const float4* g4 = (const float4*)(x + base);   // L2-hot reload
            ((float4*)sw)[swz(lane)]      = g4[lane];
            ((float4*)sw)[swz(lane + 64)] = g4[lane + 64];
            if (lane < 16) ((float4*)sw)[swz(lane + 128)] = make_float4(0.f,0.f,0.f,0.f);
        } else {
            for (int t = lane; t < FRAME_LEN; t += 64) {
                int idxr = base + t;
                if (idxr < 0) idxr = -idxr;
                if (idxr >= T_LEN) idxr = 2 * (T_LEN - 1) - idxr;
                sw[(swz(t >> 2) << 2) | (t & 3)] = x[idxr];
            }
            int t = FRAME_LEN + lane;
            sw[(swz(t >> 2) << 2) | (t & 3)] = 0.0f;
        }
        __threadfence_block();

        const float4* s4 = (const float4*)sw;
        double dtot[4];
        #pragma unroll
        for (int r = 0; r < 4; ++r) {
            const int g  = (r << 2) + qd;
            const int p0 = MIN_PERIOD + (g << 4);
            double dacc[16];
            #pragma unroll
            for (int j = 0; j < 16; ++j) dacc[j] = 0.0;
            if (g < 14) {
                const int n16 = (FRAME_LEN - p0 + 15) >> 4;
                #pragma unroll
                for (int k = 0; k < 2; ++k) {
                    const int ch = seg + (k << 4);
                    if (ch < n16) {
                        const int t  = ch << 4;
                        const int qa = t >> 2;
                        const int qw = (t + p0) >> 2;
                        float a[16], w[32];
                        #pragma unroll
                        for (int u = 0; u < 4; ++u) {
                            float4 v = s4[swz(qa + u)];
                            a[4*u+0]=v.x; a[4*u+1]=v.y; a[4*u+2]=v.z; a[4*u+3]=v.w;
                        }
                        #pragma unroll
                        for (int u = 0; u < 8; ++u) {
                            float4 v = s4[swz(qw + u)];
                            w[4*u+0]=v.x; w[4*u+1]=v.y; w[4*u+2]=v.z; w[4*u+3]=v.w;
                        }
                        #pragma unroll
                        for (int j = 0; j < 16; ++j) {
                            #pragma unroll
                            for (int i = 0; i < 16; ++i)
                                dacc[j] = fma((double)a[i], (double)w[i + j], dacc[j]);
                        }
                    }
                }
            }
            double u8[8], u4[4], u2[2], dtotal;
            #pragma unroll
            for (int i = 0; i < 8; ++i) {
                double lo = dacc[2*i], hi = dacc[2*i+1];
                double keep = s0 ? hi : lo, send = s0 ? lo : hi;
                u8[i] = keep + __shfl_xor(send, 1);
            }
            #pragma unroll
            for (int i = 0; i < 4; ++i) {
                double lo = u8[2*i], hi = u8[2*i+1];
                double keep = s1 ? hi : lo, send = s1 ? lo : hi;
                u4[i] = keep + __shfl_xor(send, 2);
            }
            #pragma unroll
            for (int i = 0; i < 2; ++i) {
                double lo = u4[2*i], hi = u4[2*i+1];
                double keep = s2 ? hi : lo, send = s2 ? lo : hi;
                u2[i] = keep + __shfl_xor(send, 4);
            }
            {
                double lo = u2[0], hi = u2[1];
                double keep = s3 ? hi : lo, send = s3 ? lo : hi;
                dtotal = keep + __shfl_xor(send, 8);
            }
            dtot[r] = ((r << 6) + lane < N_LAGS) ? dtotal : -__builtin_inf();
        }
        double dv1 = dtot[0];
        int    di1 = lane;
        #pragma unroll
        for (int r = 1; r < 4; ++r) {
            double c = dtot[r];
            if (c > dv1) { dv1 = c; di1 = (r << 6) + lane; }
        }
        #pragma unroll
        for (int m = 1; m < 64; m <<= 1) {
            double o = __shfl_xor(dv1, m);
            int   oi = __shfl_xor(di1, m);
            if (o > dv1 || (o == dv1 && oi < di1)) { dv1 = o; di1 = oi; }
        }
        if (lane == 0) emit(out, bf, di1);
    }
}

extern "C" void kernel_launch(void* const* d_in, const int* in_sizes, int n_in,
                              void* d_out, int out_size, void* d_ws, size_t ws_size,
                              hipStream_t stream) {
    const float* wav = (const float*)d_in[0]; // (64, 1, 163840) fp32
    float* out = (float*)d_out;               // (64, 641) fp32
    f0_zero<<<1, 64, 0, stream>>>();
    f0_t1<<<T1_BLOCKS, 256, 0, stream>>>(wav, out);
    f0_t23<<<T23_BLOCKS, 256, 0, stream>>>(wav, out);
}

// Round 8
// 182.622 us; speedup vs baseline: 1.0000x; 1.0000x over previous
//
#include <hip/hip_runtime.h>

// F0 via autocorrelation argmax — round 21: halve per-frame line demand.
//   SR=16000, HOP=256, FRAME_LEN=512, pad=256, T=163840, B=64, n_frames=641
//   lags p in [32,256). argmax of RAW autocorrelation == reference argmax.
//
// Evidence r13-r20: throughput pinned at ~1 frame/1100 CU-cyc across occ
// 12-49%, VGPR 32-176, DS +-40%, conflicts 0-6.5M; VALU<=36%, DS<=45%,
// MFMA<=7%, HBM 4%. Effective concurrency ~2-3 waves/CU regardless of
// residency. Only per-frame resource never varied: OUTSTANDING VECTOR-MEM
// LINES (2KB = 16 lines/frame; per-CU outstanding-line limit x ~700-1000cyc
// L3 latency => ~1 frame/1000cyc/CU — matches). r21: consecutive frames
// overlap 50% -> in the r20 8-frame loop, reuse cur2 as next frame's cur1
// (bit-identical values) and PREFETCH only the new 1KB during the current
// frame's MFMA phase. Fresh lines/frame 16 -> 8, latency off critical path.
// Falsifier: FETCH halves but t1 >= 70us -> memory acquitted, declare floor.
//
// Structure (r20): f0_t1 tier-1-only loop (1282 blocks x 4 waves x 8 frames,
// 26.1KB LDS -> 6 blocks/CU, 40 VGPR, occ 43%); rejects -> worklist;
// f0_t23 full finish (tier-1 recompute + tier-2 + tier-3, bit-identical).
//
// GEMM cast (validated r8-r20, absmax 0.0): y = frame zero-extended,
//   A[m,k]=y[k-16m], B[k,n]=y[k+32+n] => D[m,n]=AC[32+16m+n]
//   15 mfma_f32_16x16x32_f16 (NC=15; c=15 contributes exactly +0.0).
//   Staggered hi copies C_s[e]=y[e-240+s], s=0..3, CP=408 (conflict-free
//   b64 B-reads, verified r19). Reductions on VALU (DPP + permlane swaps).
// Tiers: E1 = 2^-10*Q + 0.05 ; tier-2 double-f16 split E2 = 1e-4*Q + 0.02 ;
// tier-3 fp64 register tile exact (cold).

#define SR_F 16000.0f
#define HOP 256
#define FRAME_LEN 512
#define PAD 256
#define T_LEN 163840
#define N_FRAMES 641
#define TOTAL (64 * N_FRAMES)   // 41024
#define MIN_PERIOD 32
#define N_LAGS 224
#define WPB 4              // waves per block
#define CP 408             // hi-copy stride in dwords; 408 mod 32 = 24
#define T1_DW (4 * CP)     // 1632 dw/wave (hi copies only) -> 26112 B/block
#define L0_OFF 1632        // lo even copy (t23 layout)
#define L1_OFF 2032        // lo odd copy
#define T23_DW 2432        // t23 dwords per wave slice (38912 B/block)
#define NC 15              // K-steps: c=15 contributes exactly zero
#define T1_BLOCKS 1282     // x4 waves x8 frames = 41024 exactly
#define NF 8               // frames per wave in f0_t1
#define T23_BLOCKS 768
#define T23_STRIDE (T23_BLOCKS * WPB)

typedef _Float16 half8 __attribute__((ext_vector_type(8)));
typedef float floatx4 __attribute__((ext_vector_type(4)));
typedef unsigned int uint2v __attribute__((ext_vector_type(2)));

__device__ unsigned int g_cnt2;
__device__ unsigned int g_lst2[TOTAL];

__device__ __forceinline__ int swz(int q) { return q ^ ((q >> 3) & 7); }

__device__ __forceinline__ unsigned int pkh(float a, float b) {
    unsigned short ha = __builtin_bit_cast(unsigned short, (_Float16)a);
    unsigned short hb = __builtin_bit_cast(unsigned short, (_Float16)b);
    return (unsigned int)ha | ((unsigned int)hb << 16);
}

// ---- cross-lane on the VALU pipe (keep the DS unit free) ----
#define DPP_XOR1 0xB1    // quad_perm [1,0,3,2]
#define DPP_XOR2 0x4E    // quad_perm [2,3,0,1]
#define DPP_ROR4 0x124   // row_ror:4
#define DPP_ROR8 0x128   // row_ror:8

template <int CTRL> __device__ __forceinline__ int dppi(int x) {
    return __builtin_amdgcn_update_dpp(0, x, CTRL, 0xF, 0xF, false);
}
template <int CTRL> __device__ __forceinline__ float dppf(float x) {
    return __builtin_bit_cast(float, dppi<CTRL>(__builtin_bit_cast(int, x)));
}

// permlane swaps: contract — pr[0]+pr[1] == self+partner;
// (sel ? pr[0] : pr[1]) == partner, sel = oddrow (16) / upper half (32).
__device__ __forceinline__ uint2v pl16sw(unsigned int x, bool sel) {
#if __has_builtin(__builtin_amdgcn_permlane16_swap)
    (void)sel;
    return __builtin_amdgcn_permlane16_swap(x, x, false, false);
#else
    unsigned int p = (unsigned int)__shfl_xor((int)x, 16);
    uint2v r; r[0] = sel ? p : x; r[1] = sel ? x : p; return r;
#endif
}
__device__ __forceinline__ uint2v pl32sw(unsigned int x, bool sel) {
#if __has_builtin(__builtin_amdgcn_permlane32_swap)
    (void)sel;
    return __builtin_amdgcn_permlane32_swap(x, x, false, false);
#else
    unsigned int p = (unsigned int)__shfl_xor((int)x, 32);
    uint2v r; r[0] = sel ? p : x; r[1] = sel ? x : p; return r;
#endif
}

// full-wave sum, zero DS ops
__device__ __forceinline__ float wave_sum(float x, bool oddrow, bool hihalf) {
    x += dppf<DPP_XOR1>(x);
    x += dppf<DPP_XOR2>(x);
    x += dppf<DPP_ROR4>(x);
    x += dppf<DPP_ROR8>(x);
    uint2v p = pl16sw(__builtin_bit_cast(unsigned int, x), oddrow);
    x = __builtin_bit_cast(float, p[0]) + __builtin_bit_cast(float, p[1]);
    p = pl32sw(__builtin_bit_cast(unsigned int, x), hihalf);
    x = __builtin_bit_cast(float, p[0]) + __builtin_bit_cast(float, p[1]);
    return x;
}

__device__ __forceinline__
void top2_comb(float& v1, int& i1, float& v2, float ov1, int oi1, float ov2) {
    bool take = (ov1 > v1) || (ov1 == v1 && oi1 < i1);
    float lose = take ? v1 : ov1;
    if (take) { v1 = ov1; i1 = oi1; }
    v2 = fmaxf(fmaxf(v2, ov2), lose);
}

template <int CTRL> __device__ __forceinline__
void top2_dpp(float& v1, int& i1, float& v2) {
    float ov1 = dppf<CTRL>(v1);
    int   oi1 = dppi<CTRL>(i1);
    float ov2 = dppf<CTRL>(v2);
    top2_comb(v1, i1, v2, ov1, oi1, ov2);
}

// per-lane top2 over 4 regs, then full-wave combine — zero DS ops
__device__ __forceinline__
void top2_full(floatx4 acc, int qd, int nn, bool oddrow, bool hihalf,
               float& v1, int& i1, float& v2) {
    v1 = acc[0];
    i1 = 64*qd + nn;
    v2 = -__builtin_inff();
    #pragma unroll
    for (int r = 1; r < 4; ++r) {
        float cv = (4*qd + r < 14) ? acc[r] : -__builtin_inff();
        bool take = (cv > v1);
        float lose = take ? v1 : cv;
        if (take) { v1 = cv; i1 = 64*qd + 16*r + nn; }
        v2 = fmaxf(v2, lose);
    }
    top2_dpp<DPP_XOR1>(v1, i1, v2);
    top2_dpp<DPP_XOR2>(v1, i1, v2);
    top2_dpp<DPP_ROR4>(v1, i1, v2);
    top2_dpp<DPP_ROR8>(v1, i1, v2);
    {
        uint2v a = pl16sw(__builtin_bit_cast(unsigned int, v1), oddrow);
        uint2v b = pl16sw((unsigned int)i1, oddrow);
        uint2v c = pl16sw(__builtin_bit_cast(unsigned int, v2), oddrow);
        float ov1 = __builtin_bit_cast(float, oddrow ? a[0] : a[1]);
        int   oi1 = (int)(oddrow ? b[0] : b[1]);
        float ov2 = __builtin_bit_cast(float, oddrow ? c[0] : c[1]);
        top2_comb(v1, i1, v2, ov1, oi1, ov2);
    }
    {
        uint2v a = pl32sw(__builtin_bit_cast(unsigned int, v1), hihalf);
        uint2v b = pl32sw((unsigned int)i1, hihalf);
        uint2v c = pl32sw(__builtin_bit_cast(unsigned int, v2), hihalf);
        float ov1 = __builtin_bit_cast(float, hihalf ? a[0] : a[1]);
        int   oi1 = (int)(hihalf ? b[0] : b[1]);
        float ov2 = __builtin_bit_cast(float, hihalf ? c[0] : c[1]);
        top2_comb(v1, i1, v2, ov1, oi1, ov2);
    }
}

// stage 4 staggered hi copies: C_s[e] = y[e-240+s], s=0..3 (validated r15/r19)
__device__ __forceinline__ void write_hi4(unsigned int* c0_, unsigned int* c1_,
                                          unsigned int* c2_, unsigned int* c3_,
                                          unsigned int u10, unsigned int u11,
                                          unsigned int u20, unsigned int u21,
                                          int lane) {
    *(unsigned long long*)(c0_ + 120 + 2*lane) =
        ((unsigned long long)u11 << 32) | u10;
    *(unsigned long long*)(c0_ + 248 + 2*lane) =
        ((unsigned long long)u21 << 32) | u20;
    unsigned int a  = __shfl(u10, (lane + 1) & 63);
    unsigned int bb = __shfl(u20, (lane + 1) & 63);
    unsigned int n1 = (lane == 63) ? bb : a;
    unsigned int n2 = (lane == 63) ? 0u : bb;
    unsigned int o10 = (u10 >> 16) | (u11 << 16);
    unsigned int o11 = (u11 >> 16) | (n1 << 16);
    unsigned int o20 = (u20 >> 16) | (u21 << 16);
    unsigned int o21 = (u21 >> 16) | (n2 << 16);
    *(unsigned long long*)(c1_ + 120 + 2*lane) =
        ((unsigned long long)o11 << 32) | o10;
    *(unsigned long long*)(c1_ + 248 + 2*lane) =
        ((unsigned long long)o21 << 32) | o20;
    c2_[119 + 2*lane] = u10; c2_[120 + 2*lane] = u11;
    c2_[247 + 2*lane] = u20; c2_[248 + 2*lane] = u21;
    c3_[119 + 2*lane] = o10; c3_[120 + 2*lane] = o11;
    c3_[247 + 2*lane] = o20; c3_[248 + 2*lane] = o21;
}

// stage lo parity copies (tier-2 only): L0[e]=y[e-240], L1[e]=y[e-239]
__device__ __forceinline__ void write_lo2(unsigned int* l0_, unsigned int* l1_,
                                          unsigned int u10, unsigned int u11,
                                          unsigned int u20, unsigned int u21,
                                          int lane) {
    *(unsigned long long*)(l0_ + 120 + 2*lane) =
        ((unsigned long long)u11 << 32) | u10;
    *(unsigned long long*)(l0_ + 248 + 2*lane) =
        ((unsigned long long)u21 << 32) | u20;
    unsigned int a  = __shfl(u10, (lane + 1) & 63);
    unsigned int bb = __shfl(u20, (lane + 1) & 63);
    unsigned int n1 = (lane == 63) ? bb : a;
    unsigned int n2 = (lane == 63) ? 0u : bb;
    *(unsigned long long*)(l1_ + 120 + 2*lane) =
        ((unsigned long long)(((u11 >> 16) | (n1 << 16))) << 32) |
        ((u10 >> 16) | (u11 << 16));
    *(unsigned long long*)(l1_ + 248 + 2*lane) =
        ((unsigned long long)(((u21 >> 16) | (n2 << 16))) << 32) |
        ((u20 >> 16) | (u21 << 16));
}

__device__ __forceinline__ void emit(float* out, int bf, int i1) {
    float period = (float)(i1 + MIN_PERIOD);
    float f0 = SR_F / (period + 1e-8f);
    out[bf] = fminf(fmaxf(f0, 50.0f), 500.0f);
}

__global__ void f0_zero() {
    if (threadIdx.x == 0) g_cnt2 = 0u;
}

// ======= f0_t1: tier-1-only, 8 frames per wave, 50% line reuse + prefetch ====
__global__ __launch_bounds__(256, 4) void f0_t1(const float* __restrict__ wav,
                                                float* __restrict__ out) {
    __shared__ unsigned int yw[WPB][T1_DW];   // 26112 B -> 6 blocks/CU (LDS)

    const int tid  = threadIdx.x;
    const int wv   = tid >> 6;
    const int lane = tid & 63;
    unsigned int* c0p = yw[wv];
    unsigned int* c1p = c0p + CP;
    unsigned int* c2p = c0p + 2*CP;
    unsigned int* c3p = c0p + 3*CP;

    // bijective XCD swizzle (m204): nwg=1282, q=160, r=2
    const int xcd = blockIdx.x & 7;
    const int bi  = blockIdx.x >> 3;
    const int cblk = (xcd < 2 ? xcd * 161 : 322 + (xcd - 2) * 160) + bi;
    const int bf0  = (cblk * WPB + wv) * NF;     // [0, 41024), exact cover

    const int qd = lane >> 4;
    const int nn = lane & 15;
    const int wA0 = 120 + 4*qd - 8*nn;
    const unsigned int* bhp = c0p + CP*(nn & 3) + 136 + 4*qd + 2*(nn >> 2);
    const bool oddrow = (lane & 16) != 0;
    const bool hihalf = (lane & 32) != 0;

    // one-time margin zeros: C0 bottom (A-reads reach dword 0), all tails.
    // Stable across the loop: payload rewrites cover [119..376) only.
    for (int d = lane; d < 120; d += 64) c0p[d] = 0u;
    if (lane < 28) {
        int d = 374 + lane;
        c0p[d] = 0u; c1p[d] = 0u; c2p[d] = 0u; c3p[d] = 0u;
    }

    // register-carried frame halves: cur1/cur2 valid iff `have`
    float4 cur1, cur2;
    bool have = false;

    for (int j = 0; j < NF; ++j) {
        const int bf = bf0 + j;
        const int b  = bf / N_FRAMES;
        const int f  = bf - b * N_FRAMES;
        const float* __restrict__ x = wav + (size_t)b * T_LEN;
        const int base = f * HOP - PAD;
        const bool fast = (f != 0 && f != N_FRAMES - 1);

        __threadfence_block();   // drain prev LDS reads + wait prefetch
        if (fast && !have) {     // cold entry (j==0 or after a slow frame)
            const float4* g4 = (const float4*)(x + base);
            cur1 = g4[lane];
            cur2 = g4[lane + 64];
        }

        // ---- prefetch next frame's missing half (issued before compute) ----
        bool pre = false, reuse = false;
        float4 n1, n2;
        if (j + 1 < NF) {
            const int bfn = bf + 1;
            const int bn  = bfn / N_FRAMES;
            const int fn  = bfn - bn * N_FRAMES;
            if (fn != 0 && fn != N_FRAMES - 1) {
                const float* __restrict__ xn = wav + (size_t)bn * T_LEN;
                const float4* g4n = (const float4*)(xn + fn * HOP - PAD);
                reuse = fast;            // adjacency: fn==f+1 whenever both fast
                if (!reuse) n1 = g4n[lane];
                n2 = g4n[lane + 64];
                pre = true;
            }
        }

        float qen = 0.0f;
        if (fast) {
            qen = cur1.x*cur1.x + cur1.y*cur1.y + cur1.z*cur1.z + cur1.w*cur1.w
                + cur2.x*cur2.x + cur2.y*cur2.y + cur2.z*cur2.z + cur2.w*cur2.w;
            write_hi4(c0p, c1p, c2p, c3p, pkh(cur1.x, cur1.y), pkh(cur1.z, cur1.w),
                                          pkh(cur2.x, cur2.y), pkh(cur2.z, cur2.w),
                      lane);
        } else {
            for (int t = lane; t < FRAME_LEN; t += 64) {
                int idxr = base + t;
                if (idxr < 0) idxr = -idxr;
                if (idxr >= T_LEN) idxr = 2 * (T_LEN - 1) - idxr;
                float v = x[idxr];
                qen = __builtin_fmaf(v, v, qen);
                unsigned short h = __builtin_bit_cast(unsigned short, (_Float16)v);
                ((unsigned short*)c0p)[240 + t] = h;
                ((unsigned short*)c1p)[239 + t] = h;
                ((unsigned short*)c2p)[238 + t] = h;
                ((unsigned short*)c3p)[237 + t] = h;
            }
        }
        __threadfence_block();

        qen = wave_sum(qen, oddrow, hihalf);

        // tier-1: 15 MFMA (2 chains), b64 B-reads (bit-identical to r19/r20)
        floatx4 acc0 = {0.f, 0.f, 0.f, 0.f};
        floatx4 acc1 = {0.f, 0.f, 0.f, 0.f};
        #pragma unroll
        for (int c = 0; c < NC; ++c) {
            uint4 au = *(const uint4*)(c0p + (wA0 + 16*c));
            unsigned long long bl = *(const unsigned long long*)(bhp + 16*c);
            unsigned long long br = *(const unsigned long long*)(bhp + 16*c + 2);
            uint4 bu; bu.x = (unsigned int)bl; bu.y = (unsigned int)(bl >> 32);
            bu.z = (unsigned int)br; bu.w = (unsigned int)(br >> 32);
            if (c & 1)
                acc1 = __builtin_amdgcn_mfma_f32_16x16x32_f16(
                    __builtin_bit_cast(half8, au), __builtin_bit_cast(half8, bu),
                    acc1, 0, 0, 0);
            else
                acc0 = __builtin_amdgcn_mfma_f32_16x16x32_f16(
                    __builtin_bit_cast(half8, au), __builtin_bit_cast(half8, bu),
                    acc0, 0, 0, 0);
        }
        floatx4 acc = acc0 + acc1;

        float v1, v2; int i1;
        top2_full(acc, qd, nn, oddrow, hihalf, v1, i1, v2);

        const float E1 = 9.765625e-4f * qen + 0.05f;
        if (lane == 0) {
            if (v1 - v2 > 2.0f * E1) {
                emit(out, bf, i1);
            } else {
                unsigned int ii = atomicAdd(&g_cnt2, 1u);
                g_lst2[ii] = (unsigned int)bf;
            }
        }

        // rotate register-carried halves into next frame
        if (pre) {
            cur1 = reuse ? cur2 : n1;
            cur2 = n2;
        }
        have = pre;
    }
}

// ============ f0_t23: tier-2 + tier-3 over the worklist (~15%) ============
__global__ __launch_bounds__(256, 2) void f0_t23(const float* __restrict__ wav,
                                                 float* __restrict__ out) {
    __shared__ unsigned int yw[WPB][T23_DW];   // 38912 B/block

    const int tid  = threadIdx.x;
    const int wv   = tid >> 6;
    const int lane = tid & 63;
    unsigned int* c0p = yw[wv];
    unsigned int* c1p = c0p + CP;
    unsigned int* c2p = c0p + 2*CP;
    unsigned int* c3p = c0p + 3*CP;
    unsigned int* l0p = c0p + L0_OFF;
    unsigned int* l1p = c0p + L1_OFF;

    const int qd = lane >> 4;
    const int nn = lane & 15;
    const int par = nn & 1;
    const int wA0 = 120 + 4*qd - 8*nn;
    const unsigned int* bhp = c0p + CP*(nn & 3) + 136 + 4*qd + 2*(nn >> 2);
    const int wB0old = 136 + 4*qd + ((nn - par) >> 1);
    const int seg = lane & 15;
    const bool s0 = (seg & 1), s1 = (seg & 2), s2 = (seg & 4), s3 = (seg & 8);
    const bool oddrow = (lane & 16) != 0;
    const bool hihalf = (lane & 32) != 0;

    // one-time zeros stable across items (tier-3 sw clobbers only dwords
    // 0..575 = C0 + start of C1; C1 payload is rewritten per item).
    for (int d = lane; d < 120; d += 64) l0p[d] = 0u;
    if (lane < 28) {
        int d = 374 + lane;
        c1p[d] = 0u; c2p[d] = 0u; c3p[d] = 0u; l0p[d] = 0u; l1p[d] = 0u;
    }

    const unsigned int cnt = g_cnt2;
    for (unsigned int it = blockIdx.x * WPB + wv; it < cnt; it += T23_STRIDE) {
        const int bf = (int)g_lst2[it];
        const int b  = bf / N_FRAMES;
        const int f  = bf - b * N_FRAMES;
        const float* __restrict__ x = wav + (size_t)b * T_LEN;
        const int base = f * HOP - PAD;
        const bool fast = (f != 0 && f != N_FRAMES - 1);

        __threadfence_block();
        // per-item C0 margin re-zero (tier-3 of a previous item clobbers)
        for (int d = lane; d < 120; d += 64) c0p[d] = 0u;
        if (lane < 28) c0p[374 + lane] = 0u;

        float4 c1, c2;
        float qen = 0.0f;
        if (fast) {
            const float4* g4 = (const float4*)(x + base);
            c1 = g4[lane];
            c2 = g4[lane + 64];
            qen = c1.x*c1.x + c1.y*c1.y + c1.z*c1.z + c1.w*c1.w
                + c2.x*c2.x + c2.y*c2.y + c2.z*c2.z + c2.w*c2.w;
            write_hi4(c0p, c1p, c2p, c3p, pkh(c1.x, c1.y), pkh(c1.z, c1.w),
                                          pkh(c2.x, c2.y), pkh(c2.z, c2.w), lane);
        } else {
            for (int t = lane; t < FRAME_LEN; t += 64) {
                int idxr = base + t;
                if (idxr < 0) idxr = -idxr;
                if (idxr >= T_LEN) idxr = 2 * (T_LEN - 1) - idxr;
                float v = x[idxr];
                qen = __builtin_fmaf(v, v, qen);
                unsigned short h = __builtin_bit_cast(unsigned short, (_Float16)v);
                ((unsigned short*)c0p)[240 + t] = h;
                ((unsigned short*)c1p)[239 + t] = h;
                ((unsigned short*)c2p)[238 + t] = h;
                ((unsigned short*)c3p)[237 + t] = h;
            }
        }
        __threadfence_block();

        qen = wave_sum(qen, oddrow, hihalf);

        // tier-1 acc recompute (bit-identical to f0_t1; gate already failed)
        floatx4 acc0 = {0.f, 0.f, 0.f, 0.f};
        floatx4 acc1 = {0.f, 0.f, 0.f, 0.f};
        #pragma unroll
        for (int c = 0; c < NC; ++c) {
            uint4 au = *(const uint4*)(c0p + (wA0 + 16*c));
            unsigned long long bl = *(const unsigned long long*)(bhp + 16*c);
            unsigned long long br = *(const unsigned long long*)(bhp + 16*c + 2);
            uint4 bu; bu.x = (unsigned int)bl; bu.y = (unsigned int)(bl >> 32);
            bu.z = (unsigned int)br; bu.w = (unsigned int)(br >> 32);
            if (c & 1)
                acc1 = __builtin_amdgcn_mfma_f32_16x16x32_f16(
                    __builtin_bit_cast(half8, au), __builtin_bit_cast(half8, bu),
                    acc1, 0, 0, 0);
            else
                acc0 = __builtin_amdgcn_mfma_f32_16x16x32_f16(
                    __builtin_bit_cast(half8, au), __builtin_bit_cast(half8, bu),
                    acc0, 0, 0, 0);
        }
        floatx4 acc = acc0 + acc1;

        // ==== tier-2: double-f16 split, +30 MFMA (hi*lo + lo*hi) ====
        if (fast) {
            float l0 = c1.x - (float)(_Float16)c1.x;
            float l1 = c1.y - (float)(_Float16)c1.y;
            float l2 = c1.z - (float)(_Float16)c1.z;
            float l3 = c1.w - (float)(_Float16)c1.w;
            float l4 = c2.x - (float)(_Float16)c2.x;
            float l5 = c2.y - (float)(_Float16)c2.y;
            float l6 = c2.z - (float)(_Float16)c2.z;
            float l7 = c2.w - (float)(_Float16)c2.w;
            write_lo2(l0p, l1p, pkh(l0, l1), pkh(l2, l3),
                                pkh(l4, l5), pkh(l6, l7), lane);
        } else {
            for (int t = lane; t < FRAME_LEN; t += 64) {
                int idxr = base + t;
                if (idxr < 0) idxr = -idxr;
                if (idxr >= T_LEN) idxr = 2 * (T_LEN - 1) - idxr;
                float v = x[idxr];
                float l = v - (float)(_Float16)v;
                unsigned short h = __builtin_bit_cast(unsigned short, (_Float16)l);
                ((unsigned short*)l0p)[240 + t] = h;
                ((unsigned short*)l1p)[239 + t] = h;
            }
        }
        __threadfence_block();

        const unsigned int* ybl = par ? l1p : l0p;
        #pragma unroll
        for (int c = 0; c < NC; ++c) {              // hi * lo
            uint4 au = *(const uint4*)(c0p + (wA0 + 16*c));
            const unsigned int* p = ybl + (wB0old + 16*c);
            uint4 bu; bu.x = p[0]; bu.y = p[1]; bu.z = p[2]; bu.w = p[3];
            acc = __builtin_amdgcn_mfma_f32_16x16x32_f16(
                __builtin_bit_cast(half8, au), __builtin_bit_cast(half8, bu),
                acc, 0, 0, 0);
        }
        #pragma unroll
        for (int c = 0; c < NC; ++c) {              // lo * hi
            uint4 au = *(const uint4*)(l0p + (wA0 + 16*c));
            unsigned long long bl = *(const unsigned long long*)(bhp + 16*c);
            unsigned long long br = *(const unsigned long long*)(bhp + 16*c + 2);
            uint4 bu; bu.x = (unsigned int)bl; bu.y = (unsigned int)(bl >> 32);
            bu.z = (unsigned int)br; bu.w = (unsigned int)(br >> 32);
            acc = __builtin_amdgcn_mfma_f32_16x16x32_f16(
                __builtin_bit_cast(half8, au), __builtin_bit_cast(half8, bu),
                acc, 0, 0, 0);
        }

        float v1, v2; int i1;
        top2_full(acc, qd, nn, oddrow, hihalf, v1, i1, v2);

        const float E2 = 1.0e-4f * qen + 0.02f;
        if (v1 - v2 > 2.0f * E2) {
            if (lane == 0) emit(out, bf, i1);
            continue;
        }

        // ============ tier-3: fp64 register tile (exact) ============
        float* sw = (float*)c0p;   // dwords 0..575 (C0 + C1 head; restaged)
        if (fast) {
            const float4* g4 = (const float4*)(x + base);   // L2-hot reload
            ((float4*)sw)[swz(lane)]      = g4[lane];
            ((float4*)sw)[swz(lane + 64)] = g4[lane + 64];
            if (lane < 16) ((float4*)sw)[swz(lane + 128)] = make_float4(0.f,0.f,0.f,0.f);
        } else {
            for (int t = lane; t < FRAME_LEN; t += 64) {
                int idxr = base + t;
                if (idxr < 0) idxr = -idxr;
                if (idxr >= T_LEN) idxr = 2 * (T_LEN - 1) - idxr;
                sw[(swz(t >> 2) << 2) | (t & 3)] = x[idxr];
            }
            int t = FRAME_LEN + lane;
            sw[(swz(t >> 2) << 2) | (t & 3)] = 0.0f;
        }
        __threadfence_block();

        const float4* s4 = (const float4*)sw;
        double dtot[4];
        #pragma unroll
        for (int r = 0; r < 4; ++r) {
            const int g  = (r << 2) + qd;
            const int p0 = MIN_PERIOD + (g << 4);
            double dacc[16];
            #pragma unroll
            for (int j = 0; j < 16; ++j) dacc[j] = 0.0;
            if (g < 14) {
                const int n16 = (FRAME_LEN - p0 + 15) >> 4;
                #pragma unroll
                for (int k = 0; k < 2; ++k) {
                    const int ch = seg + (k << 4);
                    if (ch < n16) {
                        const int t  = ch << 4;
                        const int qa = t >> 2;
                        const int qw = (t + p0) >> 2;
                        float a[16], w[32];
                        #pragma unroll
                        for (int u = 0; u < 4; ++u) {
                            float4 v = s4[swz(qa + u)];
                            a[4*u+0]=v.x; a[4*u+1]=v.y; a[4*u+2]=v.z; a[4*u+3]=v.w;
                        }
                        #pragma unroll
                        for (int u = 0; u < 8; ++u) {
                            float4 v = s4[swz(qw + u)];
                            w[4*u+0]=v.x; w[4*u+1]=v.y; w[4*u+2]=v.z; w[4*u+3]=v.w;
                        }
                        #pragma unroll
                        for (int j = 0; j < 16; ++j) {
                            #pragma unroll
                            for (int i = 0; i < 16; ++i)
                                dacc[j] = fma((double)a[i], (double)w[i + j], dacc[j]);
                        }
                    }
                }
            }
            double u8[8], u4[4], u2[2], dtotal;
            #pragma unroll
            for (int i = 0; i < 8; ++i) {
                double lo = dacc[2*i], hi = dacc[2*i+1];
                double keep = s0 ? hi : lo, send = s0 ? lo : hi;
                u8[i] = keep + __shfl_xor(send, 1);
            }
            #pragma unroll
            for (int i = 0; i < 4; ++i) {
                double lo = u8[2*i], hi = u8[2*i+1];
                double keep = s1 ? hi : lo, send = s1 ? lo : hi;
                u4[i] = keep + __shfl_xor(send, 2);
            }
            #pragma unroll
            for (int i = 0; i < 2; ++i) {
                double lo = u4[2*i], hi = u4[2*i+1];
                double keep = s2 ? hi : lo, send = s2 ? lo : hi;
                u2[i] = keep + __shfl_xor(send, 4);
            }
            {
                double lo = u2[0], hi = u2[1];
                double keep = s3 ? hi : lo, send = s3 ? lo : hi;
                dtotal = keep + __shfl_xor(send, 8);
            }
            dtot[r] = ((r << 6) + lane < N_LAGS) ? dtotal : -__builtin_inf();
        }
        double dv1 = dtot[0];
        int    di1 = lane;
        #pragma unroll
        for (int r = 1; r < 4; ++r) {
            double c = dtot[r];
            if (c > dv1) { dv1 = c; di1 = (r << 6) + lane; }
        }
        #pragma unroll
        for (int m = 1; m < 64; m <<= 1) {
            double o = __shfl_xor(dv1, m);
            int   oi = __shfl_xor(di1, m);
            if (o > dv1 || (o == dv1 && oi < di1)) { dv1 = o; di1 = oi; }
        }
        if (lane == 0) emit(out, bf, di1);
    }
}

extern "C" void kernel_launch(void* const* d_in, const int* in_sizes, int n_in,
                              void* d_out, int out_size, void* d_ws, size_t ws_size,
                              hipStream_t stream) {
    const float* wav = (const float*)d_in[0]; // (64, 1, 163840) fp32
    float* out = (float*)d_out;               // (64, 641) fp32
    f0_zero<<<1, 64, 0, stream>>>();
    f0_t1<<<T1_BLOCKS, 256, 0, stream>>>(wav, out);
    f0_t23<<<T23_BLOCKS, 256, 0, stream>>>(wav, out);
}

// Round 9
// 130.140 us; speedup vs baseline: 1.4033x; 1.4033x over previous
//
#include <hip/hip_runtime.h>

// F0 via autocorrelation argmax — round 22: REVERT to measured-best (r16).
//   SR=16000, HOP=256, FRAME_LEN=512, pad=256, T=163840, B=64, n_frames=641
//   lags p in [32,256). argmax of RAW autocorrelation == reference argmax.
//
// Session ledger (r13-r21): per-frame throughput invariant ~437ns/frame/CU
// across occupancy 12-49%, VGPR 32-176, DS ops +-40%, conflicts 0-6.5M,
// FETCH 21-25MB, and five different execution structures (one-shot,
// worklist pipeline, pair-ILP, persistent grid, prefetch/reuse). All
// counter-visible pipes acquitted (VALU<=36%, MFMA<=7%, DS<=60%, HBM<=5%).
// r21's register-reuse was defeated by allocator spill (WRITE 0.46->7.1MB).
// Remaining hypotheses (clock governor at ~28% duty, invisible per-CU
// memory queueing) are not addressable from source. Locking in the best:
// r16 = 130.34us total, ~70us dispatch, absmax 0.0.
//
// Structure: 10256 blocks x 4 waves, one frame per wave, straight-line
// 3-tier body. r13 zero-conflict parity LDS layout. Reductions on VALU:
// stages 1,2 quad_perm DPP; 4,8 row_ror DPP; 16,32 permlane16/32_swap
// (fail-safe: wrong orientation inflates v2 -> gates reject -> exact
// tier-3). NC=15 (c=15 B-frags all zero -> contributes exactly +0.0).
//
// GEMM cast (validated r8-r21, absmax 0.0): y = frame zero-extended,
//   A[m,k]=y[k-16m], B[k,n]=y[k+32+n] => D[m,n]=AC[32+16m+n]
//   15 mfma_f32_16x16x32_f16 (K=480), two parity LDS copies for B-align.
// Tiers: E1 = 2^-10*Q + 0.05 ; tier-2 double-f16 split E2 = 1e-4*Q + 0.02 ;
// tier-3 fp64 register tile exact (cold).

#define SR_F 16000.0f
#define HOP 256
#define FRAME_LEN 512
#define PAD 256
#define T_LEN 163840
#define N_FRAMES 641
#define MIN_PERIOD 32
#define N_LAGS 224
#define WPB 4            // waves per block, one frame per wave
#define NC 15            // K-steps: c=15 contributes exactly zero

typedef _Float16 half8 __attribute__((ext_vector_type(8)));
typedef float floatx4 __attribute__((ext_vector_type(4)));
typedef unsigned int uint2v __attribute__((ext_vector_type(2)));

__device__ __forceinline__ int swz(int q) { return q ^ ((q >> 3) & 7); }

__device__ __forceinline__ unsigned int pkh(float a, float b) {
    unsigned short ha = __builtin_bit_cast(unsigned short, (_Float16)a);
    unsigned short hb = __builtin_bit_cast(unsigned short, (_Float16)b);
    return (unsigned int)ha | ((unsigned int)hb << 16);
}

// ---- cross-lane on the VALU pipe (keep the DS unit free) ----
#define DPP_XOR1 0xB1    // quad_perm [1,0,3,2]
#define DPP_XOR2 0x4E    // quad_perm [2,3,0,1]
#define DPP_ROR4 0x124   // row_ror:4
#define DPP_ROR8 0x128   // row_ror:8

template <int CTRL> __device__ __forceinline__ int dppi(int x) {
    return __builtin_amdgcn_update_dpp(0, x, CTRL, 0xF, 0xF, false);
}
template <int CTRL> __device__ __forceinline__ float dppf(float x) {
    return __builtin_bit_cast(float, dppi<CTRL>(__builtin_bit_cast(int, x)));
}

// permlane swaps: contract — pr[0]+pr[1] == self+partner;
// (sel ? pr[0] : pr[1]) == partner, sel = oddrow (16) / upper half (32).
__device__ __forceinline__ uint2v pl16sw(unsigned int x, bool sel) {
#if __has_builtin(__builtin_amdgcn_permlane16_swap)
    (void)sel;
    return __builtin_amdgcn_permlane16_swap(x, x, false, false);
#else
    unsigned int p = (unsigned int)__shfl_xor((int)x, 16);
    uint2v r; r[0] = sel ? p : x; r[1] = sel ? x : p; return r;
#endif
}
__device__ __forceinline__ uint2v pl32sw(unsigned int x, bool sel) {
#if __has_builtin(__builtin_amdgcn_permlane32_swap)
    (void)sel;
    return __builtin_amdgcn_permlane32_swap(x, x, false, false);
#else
    unsigned int p = (unsigned int)__shfl_xor((int)x, 32);
    uint2v r; r[0] = sel ? p : x; r[1] = sel ? x : p; return r;
#endif
}

// full-wave sum, zero DS ops
__device__ __forceinline__ float wave_sum(float x, bool oddrow, bool hihalf) {
    x += dppf<DPP_XOR1>(x);
    x += dppf<DPP_XOR2>(x);
    x += dppf<DPP_ROR4>(x);
    x += dppf<DPP_ROR8>(x);
    uint2v p = pl16sw(__builtin_bit_cast(unsigned int, x), oddrow);
    x = __builtin_bit_cast(float, p[0]) + __builtin_bit_cast(float, p[1]);
    p = pl32sw(__builtin_bit_cast(unsigned int, x), hihalf);
    x = __builtin_bit_cast(float, p[0]) + __builtin_bit_cast(float, p[1]);
    return x;
}

__device__ __forceinline__
void top2_comb(float& v1, int& i1, float& v2, float ov1, int oi1, float ov2) {
    bool take = (ov1 > v1) || (ov1 == v1 && oi1 < i1);
    float lose = take ? v1 : ov1;
    if (take) { v1 = ov1; i1 = oi1; }
    v2 = fmaxf(fmaxf(v2, ov2), lose);
}

template <int CTRL> __device__ __forceinline__
void top2_dpp(float& v1, int& i1, float& v2) {
    float ov1 = dppf<CTRL>(v1);
    int   oi1 = dppi<CTRL>(i1);
    float ov2 = dppf<CTRL>(v2);
    top2_comb(v1, i1, v2, ov1, oi1, ov2);
}

// per-lane top2 over 4 regs, then full-wave combine — zero DS ops
__device__ __forceinline__
void top2_full(floatx4 acc, int qd, int nn, bool oddrow, bool hihalf,
               float& v1, int& i1, float& v2) {
    v1 = acc[0];
    i1 = 64*qd + nn;
    v2 = -__builtin_inff();
    #pragma unroll
    for (int r = 1; r < 4; ++r) {
        float cv = (4*qd + r < 14) ? acc[r] : -__builtin_inff();
        bool take = (cv > v1);
        float lose = take ? v1 : cv;
        if (take) { v1 = cv; i1 = 64*qd + 16*r + nn; }
        v2 = fmaxf(v2, lose);
    }
    top2_dpp<DPP_XOR1>(v1, i1, v2);
    top2_dpp<DPP_XOR2>(v1, i1, v2);
    top2_dpp<DPP_ROR4>(v1, i1, v2);
    top2_dpp<DPP_ROR8>(v1, i1, v2);
    {   // stage 16 via permlane16_swap (partner select per contract)
        uint2v a = pl16sw(__builtin_bit_cast(unsigned int, v1), oddrow);
        uint2v b = pl16sw((unsigned int)i1, oddrow);
        uint2v c = pl16sw(__builtin_bit_cast(unsigned int, v2), oddrow);
        float ov1 = __builtin_bit_cast(float, oddrow ? a[0] : a[1]);
        int   oi1 = (int)(oddrow ? b[0] : b[1]);
        float ov2 = __builtin_bit_cast(float, oddrow ? c[0] : c[1]);
        top2_comb(v1, i1, v2, ov1, oi1, ov2);
    }
    {   // stage 32 via permlane32_swap
        uint2v a = pl32sw(__builtin_bit_cast(unsigned int, v1), hihalf);
        uint2v b = pl32sw((unsigned int)i1, hihalf);
        uint2v c = pl32sw(__builtin_bit_cast(unsigned int, v2), hihalf);
        float ov1 = __builtin_bit_cast(float, hihalf ? a[0] : a[1]);
        int   oi1 = (int)(hihalf ? b[0] : b[1]);
        float ov2 = __builtin_bit_cast(float, hihalf ? c[0] : c[1]);
        top2_comb(v1, i1, v2, ov1, oi1, ov2);
    }
}

// stage parity copies: even (elem e = Y[e-240]) + odd (elem e = Y[e-239])
__device__ __forceinline__ void write_copies(unsigned int* e, unsigned int* o,
                                             unsigned int u10, unsigned int u11,
                                             unsigned int u20, unsigned int u21,
                                             int lane) {
    e[120 + 2*lane] = u10;  e[121 + 2*lane] = u11;
    e[248 + 2*lane] = u20;  e[249 + 2*lane] = u21;
    unsigned int a  = __shfl(u10, (lane + 1) & 63);
    unsigned int bb = __shfl(u20, (lane + 1) & 63);
    unsigned int n1 = (lane == 63) ? bb : a;
    unsigned int n2 = (lane == 63) ? 0u : bb;
    o[120 + 2*lane] = (u10 >> 16) | (u11 << 16);
    o[121 + 2*lane] = (u11 >> 16) | (n1 << 16);
    o[248 + 2*lane] = (u20 >> 16) | (u21 << 16);
    o[249 + 2*lane] = (u21 >> 16) | (n2 << 16);
    if (lane == 0) o[119] = u10 << 16;   // {Y[-1]=0, Y[0]}
}

__global__ __launch_bounds__(256, 4) void f0_kernel(const float* __restrict__ wav,
                                                    float* __restrict__ out) {
    // per-wave slice: ye(400) yo(400) le(400) lo(400) dwords = 6400 B
    __shared__ unsigned int yw[WPB][1600];

    const int tid  = threadIdx.x;
    const int wv   = tid >> 6;
    const int lane = tid & 63;
    unsigned int* ye  = yw[wv];
    unsigned int* yo  = ye + 400;
    unsigned int* le  = ye + 800;
    unsigned int* loo = ye + 1200;

    // XCD-contiguous frame assignment: 10256 blocks = 8*1282.
    const int xcd = blockIdx.x & 7;
    const int idx = blockIdx.x >> 3;
    const int bf  = (xcd * 1282 + idx) * WPB + wv;   // all 41024 covered
    const int b   = bf / N_FRAMES;
    const int f   = bf - b * N_FRAMES;
    const float* __restrict__ x = wav + (size_t)b * T_LEN;
    const int base = f * HOP - PAD;
    const bool fast = (f != 0 && f != N_FRAMES - 1);

    const int qd = lane >> 4;       // quad
    const int nn = lane & 15;       // A-row m / B-col n
    const int par = nn & 1;
    const unsigned int* ybh = par ? yo : ye;
    const unsigned int* ybl = par ? loo : le;
    const int wA0 = 120 + 4*qd - 8*nn;
    const int wB0 = 136 + 4*qd + ((nn - par) >> 1);
    const int seg = lane & 15;
    const bool s0 = (seg & 1), s1 = (seg & 2), s2 = (seg & 4), s3 = (seg & 8);
    const bool oddrow = (lane & 16) != 0;
    const bool hihalf = (lane & 32) != 0;

    // ---- issue global loads first ----
    float4 c1, c2;
    if (fast) {
        const float4* g4 = (const float4*)(x + base);   // aligned, in-bounds
        c1 = g4[lane];
        c2 = g4[lane + 64];
    }
    // zero margins: dwords [0,120) and [375,400) of both parity copies
    ye[lane] = 0u; yo[lane] = 0u;
    if (lane < 56) { ye[64 + lane] = 0u; yo[64 + lane] = 0u; }
    if (lane < 25) { ye[375 + lane] = 0u; yo[375 + lane] = 0u; }

    float qen = 0.0f;
    if (fast) {
        qen = c1.x*c1.x + c1.y*c1.y + c1.z*c1.z + c1.w*c1.w
            + c2.x*c2.x + c2.y*c2.y + c2.z*c2.z + c2.w*c2.w;
        write_copies(ye, yo, pkh(c1.x, c1.y), pkh(c1.z, c1.w),
                             pkh(c2.x, c2.y), pkh(c2.z, c2.w), lane);
    } else {
        for (int t = lane; t < FRAME_LEN; t += 64) {
            int idxr = base + t;
            if (idxr < 0) idxr = -idxr;
            if (idxr >= T_LEN) idxr = 2 * (T_LEN - 1) - idxr;
            float v = x[idxr];
            qen = __builtin_fmaf(v, v, qen);
            unsigned short h = __builtin_bit_cast(unsigned short, (_Float16)v);
            ((unsigned short*)ye)[240 + t] = h;
            ((unsigned short*)yo)[239 + t] = h;
        }
    }
    __threadfence_block();

    qen = wave_sum(qen, oddrow, hihalf);

    // ---------------- tier-1: 15 MFMA (2 chains) ----------------
    floatx4 acc0 = {0.f, 0.f, 0.f, 0.f};
    floatx4 acc1 = {0.f, 0.f, 0.f, 0.f};
    #pragma unroll
    for (int c = 0; c < NC; ++c) {
        uint4 au = *(const uint4*)(ye + (wA0 + 16*c));
        const unsigned int* pb = ybh + (wB0 + 16*c);
        uint4 bu; bu.x = pb[0]; bu.y = pb[1]; bu.z = pb[2]; bu.w = pb[3];
        if (c & 1)
            acc1 = __builtin_amdgcn_mfma_f32_16x16x32_f16(
                __builtin_bit_cast(half8, au), __builtin_bit_cast(half8, bu),
                acc1, 0, 0, 0);
        else
            acc0 = __builtin_amdgcn_mfma_f32_16x16x32_f16(
                __builtin_bit_cast(half8, au), __builtin_bit_cast(half8, bu),
                acc0, 0, 0, 0);
    }
    floatx4 acc = acc0 + acc1;

    float v1, v2; int i1;
    top2_full(acc, qd, nn, oddrow, hihalf, v1, i1, v2);

    const float E1 = 9.765625e-4f * qen + 0.05f;
    if (v1 - v2 > 2.0f * E1) {
        if (lane == 0) {
            float period = (float)(i1 + MIN_PERIOD);
            float f0 = SR_F / (period + 1e-8f);
            out[bf] = fminf(fmaxf(f0, 50.0f), 500.0f);
        }
        return;
    }

    // ==== tier-2: double-f16 split, +30 MFMA (hi*lo + lo*hi), ~15% ====
    le[lane] = 0u; loo[lane] = 0u;
    if (lane < 56) { le[64 + lane] = 0u; loo[64 + lane] = 0u; }
    if (lane < 25) { le[375 + lane] = 0u; loo[375 + lane] = 0u; }
    if (fast) {
        float l0 = c1.x - (float)(_Float16)c1.x;
        float l1 = c1.y - (float)(_Float16)c1.y;
        float l2 = c1.z - (float)(_Float16)c1.z;
        float l3 = c1.w - (float)(_Float16)c1.w;
        float l4 = c2.x - (float)(_Float16)c2.x;
        float l5 = c2.y - (float)(_Float16)c2.y;
        float l6 = c2.z - (float)(_Float16)c2.z;
        float l7 = c2.w - (float)(_Float16)c2.w;
        write_copies(le, loo, pkh(l0, l1), pkh(l2, l3),
                              pkh(l4, l5), pkh(l6, l7), lane);
    } else {
        for (int t = lane; t < FRAME_LEN; t += 64) {
            int idxr = base + t;
            if (idxr < 0) idxr = -idxr;
            if (idxr >= T_LEN) idxr = 2 * (T_LEN - 1) - idxr;
            float v = x[idxr];
            float l = v - (float)(_Float16)v;
            unsigned short h = __builtin_bit_cast(unsigned short, (_Float16)l);
            ((unsigned short*)le)[240 + t] = h;
            ((unsigned short*)loo)[239 + t] = h;
        }
    }
    __threadfence_block();

    #pragma unroll
    for (int c = 0; c < NC; ++c) {              // hi * lo
        uint4 au = *(const uint4*)(ye + (wA0 + 16*c));
        const unsigned int* p = ybl + (wB0 + 16*c);
        uint4 bu; bu.x = p[0]; bu.y = p[1]; bu.z = p[2]; bu.w = p[3];
        acc = __builtin_amdgcn_mfma_f32_16x16x32_f16(
            __builtin_bit_cast(half8, au), __builtin_bit_cast(half8, bu),
            acc, 0, 0, 0);
    }
    #pragma unroll
    for (int c = 0; c < NC; ++c) {              // lo * hi
        uint4 au = *(const uint4*)(le + (wA0 + 16*c));
        const unsigned int* p = ybh + (wB0 + 16*c);
        uint4 bu; bu.x = p[0]; bu.y = p[1]; bu.z = p[2]; bu.w = p[3];
        acc = __builtin_amdgcn_mfma_f32_16x16x32_f16(
            __builtin_bit_cast(half8, au), __builtin_bit_cast(half8, bu),
            acc, 0, 0, 0);
    }

    top2_full(acc, qd, nn, oddrow, hihalf, v1, i1, v2);

    const float E2 = 1.0e-4f * qen + 0.02f;
    if (v1 - v2 > 2.0f * E2) {
        if (lane == 0) {
            float period = (float)(i1 + MIN_PERIOD);
            float f0 = SR_F / (period + 1e-8f);
            out[bf] = fminf(fmaxf(f0, 50.0f), 500.0f);
        }
        return;
    }

    // ============ tier-3: fp64 register tile (exact), ~1-2% ============
    float* sw = (float*)ye;   // 576 floats over ye+yo (terminal use)
    if (fast) {
        const float4* g4 = (const float4*)(x + base);   // L2-hot reload
        ((float4*)sw)[swz(lane)]      = g4[lane];
        ((float4*)sw)[swz(lane + 64)] = g4[lane + 64];
        if (lane < 16) ((float4*)sw)[swz(lane + 128)] = make_float4(0.f,0.f,0.f,0.f);
    } else {
        for (int t = lane; t < FRAME_LEN; t += 64) {
            int idxr = base + t;
            if (idxr < 0) idxr = -idxr;
            if (idxr >= T_LEN) idxr = 2 * (T_LEN - 1) - idxr;
            sw[(swz(t >> 2) << 2) | (t & 3)] = x[idxr];
        }
        int t = FRAME_LEN + lane;
        sw[(swz(t >> 2) << 2) | (t & 3)] = 0.0f;
    }
    __threadfence_block();

    const float4* s4 = (const float4*)sw;
    double dtot[4];
    #pragma unroll
    for (int r = 0; r < 4; ++r) {
        const int g  = (r << 2) + qd;
        const int p0 = MIN_PERIOD + (g << 4);
        double dacc[16];
        #pragma unroll
        for (int j = 0; j < 16; ++j) dacc[j] = 0.0;
        if (g < 14) {
            const int n16 = (FRAME_LEN - p0 + 15) >> 4;
            #pragma unroll
            for (int k = 0; k < 2; ++k) {
                const int ch = seg + (k << 4);
                if (ch < n16) {
                    const int t  = ch << 4;
                    const int qa = t >> 2;
                    const int qw = (t + p0) >> 2;
                    float a[16], w[32];
                    #pragma unroll
                    for (int u = 0; u < 4; ++u) {
                        float4 v = s4[swz(qa + u)];
                        a[4*u+0]=v.x; a[4*u+1]=v.y; a[4*u+2]=v.z; a[4*u+3]=v.w;
                    }
                    #pragma unroll
                    for (int u = 0; u < 8; ++u) {
                        float4 v = s4[swz(qw + u)];
                        w[4*u+0]=v.x; w[4*u+1]=v.y; w[4*u+2]=v.z; w[4*u+3]=v.w;
                    }
                    #pragma unroll
                    for (int j = 0; j < 16; ++j) {
                        #pragma unroll
                        for (int i = 0; i < 16; ++i)
                            dacc[j] = fma((double)a[i], (double)w[i + j], dacc[j]);
                    }
                }
            }
        }
        double u8[8], u4[4], u2[2], dtotal;
        #pragma unroll
        for (int i = 0; i < 8; ++i) {
            double lo = dacc[2*i], hi = dacc[2*i+1];
            double keep = s0 ? hi : lo, send = s0 ? lo : hi;
            u8[i] = keep + __shfl_xor(send, 1);
        }
        #pragma unroll
        for (int i = 0; i < 4; ++i) {
            double lo = u8[2*i], hi = u8[2*i+1];
            double keep = s1 ? hi : lo, send = s1 ? lo : hi;
            u4[i] = keep + __shfl_xor(send, 2);
        }
        #pragma unroll
        for (int i = 0; i < 2; ++i) {
            double lo = u4[2*i], hi = u4[2*i+1];
            double keep = s2 ? hi : lo, send = s2 ? lo : hi;
            u2[i] = keep + __shfl_xor(send, 4);
        }
        {
            double lo = u2[0], hi = u2[1];
            double keep = s3 ? hi : lo, send = s3 ? lo : hi;
            dtotal = keep + __shfl_xor(send, 8);
        }
        dtot[r] = ((r << 6) + lane < N_LAGS) ? dtotal : -__builtin_inf();
    }
    double dv1 = dtot[0];
    int    di1 = lane;
    #pragma unroll
    for (int r = 1; r < 4; ++r) {
        double c = dtot[r];
        if (c > dv1) { dv1 = c; di1 = (r << 6) + lane; }
    }
    #pragma unroll
    for (int m = 1; m < 64; m <<= 1) {
        double o = __shfl_xor(dv1, m);
        int   oi = __shfl_xor(di1, m);
        if (o > dv1 || (o == dv1 && oi < di1)) { dv1 = o; di1 = oi; }
    }
    if (lane == 0) {
        float period = (float)(di1 + MIN_PERIOD);
        float f0 = SR_F / (period + 1e-8f);
        out[bf] = fminf(fmaxf(f0, 50.0f), 500.0f);
    }
}

extern "C" void kernel_launch(void* const* d_in, const int* in_sizes, int n_in,
                              void* d_out, int out_size, void* d_ws, size_t ws_size,
                              hipStream_t stream) {
    const float* wav = (const float*)d_in[0]; // (64, 1, 163840) fp32
    float* out = (float*)d_out;               // (64, 641) fp32
    const int n_blocks = (64 * N_FRAMES) / WPB;   // 10256 = 8 * 1282
    f0_kernel<<<n_blocks, 256, 0, stream>>>(wav, out);
}